// Round 1
// baseline (272.081 us; speedup 1.0000x reference)
//
#include <hip/hip_runtime.h>

typedef unsigned short u16;
typedef __attribute__((ext_vector_type(8))) short s8v;   // 8 bf16 in 4 VGPRs
typedef __attribute__((ext_vector_type(4))) float f4v;   // MFMA accumulator

#define B_N 8
#define L_Q 2048
#define L_K 2048
#define DIM 128
#define KT  64

__device__ __forceinline__ u16 f2bf(float f) {
  union { float f; unsigned u; } v; v.f = f;
  return (u16)((v.u + 0x7fffu + ((v.u >> 16) & 1u)) >> 16);  // RTN-even
}

// ---------------------------------------------------------------------------
// Projections: q = (query @ Wq) * (1/sqrt(128)) * log2(e)   [bf16]
//              k =  key   @ Wk                              [bf16]
//              vt = (value @ Wv)^T  (layout [b][d][k])      [bf16]
// grid 768 = 3 * (8 batches * 32 row-tiles of 64), block 256
// ---------------------------------------------------------------------------
__global__ __launch_bounds__(256) void proj_all(
    const float* __restrict__ query, const float* __restrict__ key,
    const float* __restrict__ value, const float* __restrict__ Wq,
    const float* __restrict__ Wk, const float* __restrict__ Wv,
    u16* __restrict__ qp, u16* __restrict__ kp, u16* __restrict__ vt) {
  __shared__ float Xl[64][129];   // +1 pad: conflict-free column reads
  const int tid = threadIdx.x;
  const int bi = blockIdx.x;
  const int which = bi >> 8;          // 0=q 1=k 2=v
  const int sub = bi & 255;
  const int b = sub >> 5;
  const int k0 = (sub & 31) * 64;
  const float* X = (which == 0) ? query : (which == 1) ? key : value;
  const float* W = (which == 0) ? Wq : (which == 1) ? Wk : Wv;
  const float scale = (which == 0) ? (1.44269504089f / 11.3137084990f) : 1.0f;

  const float* Xb = X + ((size_t)b * L_Q + k0) * DIM;
#pragma unroll
  for (int r = 0; r < 8; ++r) {
    int f4i = tid + r * 256;                  // 2048 float4 chunks
    float4 x4 = *(const float4*)(Xb + f4i * 4);
    int row = f4i >> 5, c = (f4i & 31) * 4;
    Xl[row][c] = x4.x; Xl[row][c + 1] = x4.y;
    Xl[row][c + 2] = x4.z; Xl[row][c + 3] = x4.w;
  }
  __syncthreads();

  const int kkb = tid & 15;       // base row (of 4: +16t)
  const int d0 = (tid >> 4) * 8;  // 8 output cols
  float acc[4][8];
#pragma unroll
  for (int t = 0; t < 4; ++t)
#pragma unroll
    for (int i = 0; i < 8; ++i) acc[t][i] = 0.f;

#pragma unroll 4
  for (int j = 0; j < 128; ++j) {
    float4 wa = *(const float4*)(W + j * DIM + d0);
    float4 wb = *(const float4*)(W + j * DIM + d0 + 4);
    float wv[8] = {wa.x, wa.y, wa.z, wa.w, wb.x, wb.y, wb.z, wb.w};
    float xv[4] = {Xl[kkb][j], Xl[kkb + 16][j], Xl[kkb + 32][j], Xl[kkb + 48][j]};
#pragma unroll
    for (int t = 0; t < 4; ++t)
#pragma unroll
      for (int i = 0; i < 8; ++i) acc[t][i] = fmaf(xv[t], wv[i], acc[t][i]);
  }

  if (which < 2) {
    u16* Y = ((which == 0) ? qp : kp) + ((size_t)b * L_Q + k0) * DIM;
#pragma unroll
    for (int t = 0; t < 4; ++t) {
      s8v pk;
#pragma unroll
      for (int i = 0; i < 8; ++i) pk[i] = (short)f2bf(acc[t][i] * scale);
      *(s8v*)(Y + (size_t)(kkb + 16 * t) * DIM + d0) = pk;
    }
  } else {
    u16* Y = vt + (size_t)b * DIM * L_K;
#pragma unroll
    for (int t = 0; t < 4; ++t)
#pragma unroll
      for (int i = 0; i < 8; ++i)
        Y[(size_t)(d0 + i) * L_K + (k0 + kkb + 16 * t)] = f2bf(acc[t][i]);
  }
}

// ---------------------------------------------------------------------------
// Flash attention: grid 256 (b = blockIdx&7 -> XCD-local K/V), block 256.
// Wave w owns q rows [q0+16w, q0+16w+16); online softmax in log2 domain
// (log2e folded into q projection). 16x16x32 bf16 MFMA throughout.
// ---------------------------------------------------------------------------
__global__ __launch_bounds__(256) void flash(
    const u16* __restrict__ qp, const u16* __restrict__ kp,
    const u16* __restrict__ vt, const int* __restrict__ mask,
    float* __restrict__ out) {
  __shared__ __align__(16) u16 Kl[KT][DIM + 8];     // [64][136]
  __shared__ __align__(16) u16 Vl[DIM][KT + 8];     // [128][72]  (V^T tile)
  __shared__ __align__(16) u16 Pl[4][16][KT + 8];   // per-wave P

  const int tid = threadIdx.x;
  const int bi = blockIdx.x;
  const int b = bi & 7;             // 8 batches round-robin over 8 XCDs
  const int q0 = (bi >> 3) * 64;
  const int w = tid >> 6;
  const int lane = tid & 63;
  const int ln = lane & 15;
  const int quad = lane >> 4;

  const u16* Qb = qp + (size_t)b * L_Q * DIM;
  const u16* Kb = kp + (size_t)b * L_K * DIM;
  const u16* Vb = vt + (size_t)b * DIM * L_K;
  const int* mb = mask + b * L_K;

  // Q fragments, resident across the whole K loop. A[m=ln][k=32ks+8quad+j]
  s8v aq[4];
  const int qrow = q0 + w * 16 + ln;
#pragma unroll
  for (int ks = 0; ks < 4; ++ks)
    aq[ks] = *(const s8v*)(Qb + (size_t)qrow * DIM + ks * 32 + quad * 8);

  f4v o[8];
#pragma unroll
  for (int i = 0; i < 8; ++i) o[i] = (f4v){0.f, 0.f, 0.f, 0.f};
  float mrow[4] = {-__builtin_inff(), -__builtin_inff(), -__builtin_inff(), -__builtin_inff()};
  float lrow[4] = {0.f, 0.f, 0.f, 0.f};

  for (int it = 0; it < L_K / KT; ++it) {
    const int k0 = it * KT;
    // stage K tile [64][128] (row-major, coalesced 16B)
#pragma unroll
    for (int r = 0; r < 4; ++r) {
      int c16 = tid + r * 256;                 // 1024 chunks, 16/row
      int row = c16 >> 4, cc = (c16 & 15) * 8;
      *(s8v*)&Kl[row][cc] = *(const s8v*)(Kb + (size_t)(k0 + row) * DIM + cc);
    }
    // stage V^T tile [128][64]
#pragma unroll
    for (int r = 0; r < 4; ++r) {
      int c16 = tid + r * 256;                 // 1024 chunks, 8/row
      int row = c16 >> 3, cc = (c16 & 7) * 8;
      *(s8v*)&Vl[row][cc] = *(const s8v*)(Vb + (size_t)row * L_K + k0 + cc);
    }
    __syncthreads();

    // S = Q K^T (log2-scaled). 4 n-tiles of 16 keys.
    f4v s[4];
#pragma unroll
    for (int nt = 0; nt < 4; ++nt) s[nt] = (f4v){0.f, 0.f, 0.f, 0.f};
#pragma unroll
    for (int ks = 0; ks < 4; ++ks) {
#pragma unroll
      for (int nt = 0; nt < 4; ++nt) {
        s8v bk = *(const s8v*)&Kl[nt * 16 + ln][ks * 32 + quad * 8];
        s[nt] = __builtin_amdgcn_mfma_f32_16x16x32_bf16(aq[ks], bk, s[nt], 0, 0, 0);
      }
    }
    // additive mask
#pragma unroll
    for (int nt = 0; nt < 4; ++nt) {
      if (mb[k0 + nt * 16 + ln] == 0) {
        s[nt][0] = -__builtin_inff(); s[nt][1] = -__builtin_inff();
        s[nt][2] = -__builtin_inff(); s[nt][3] = -__builtin_inff();
      }
    }
    // row max over 64 keys: in-lane over nt, then 16-lane butterfly
    float rmax[4];
#pragma unroll
    for (int r = 0; r < 4; ++r)
      rmax[r] = fmaxf(fmaxf(s[0][r], s[1][r]), fmaxf(s[2][r], s[3][r]));
#pragma unroll
    for (int off = 8; off >= 1; off >>= 1)
#pragma unroll
      for (int r = 0; r < 4; ++r)
        rmax[r] = fmaxf(rmax[r], __shfl_xor(rmax[r], off, 64));

    float alpha[4];
#pragma unroll
    for (int r = 0; r < 4; ++r) {
      float mn = fmaxf(mrow[r], rmax[r]);
      alpha[r] = exp2f(mrow[r] - mn);
      mrow[r] = mn;
    }
    // p = 2^(s-m); row sums
#pragma unroll
    for (int nt = 0; nt < 4; ++nt)
#pragma unroll
      for (int r = 0; r < 4; ++r) s[nt][r] = exp2f(s[nt][r] - mrow[r]);
    float rsum[4];
#pragma unroll
    for (int r = 0; r < 4; ++r)
      rsum[r] = (s[0][r] + s[1][r]) + (s[2][r] + s[3][r]);
#pragma unroll
    for (int off = 8; off >= 1; off >>= 1)
#pragma unroll
      for (int r = 0; r < 4; ++r) rsum[r] += __shfl_xor(rsum[r], off, 64);
#pragma unroll
    for (int r = 0; r < 4; ++r) lrow[r] = lrow[r] * alpha[r] + rsum[r];

    // P -> LDS (C-layout scatter), wave-private so no barrier needed
#pragma unroll
    for (int nt = 0; nt < 4; ++nt)
#pragma unroll
      for (int r = 0; r < 4; ++r)
        Pl[w][quad * 4 + r][nt * 16 + ln] = f2bf(s[nt][r]);

    // rescale O
#pragma unroll
    for (int n2 = 0; n2 < 8; ++n2)
#pragma unroll
      for (int r = 0; r < 4; ++r) o[n2][r] *= alpha[r];

    // O += P V  (A from Pl in A-layout, B from V^T tile)
#pragma unroll
    for (int kv = 0; kv < 2; ++kv) {
      s8v ap = *(const s8v*)&Pl[w][ln][kv * 32 + quad * 8];
#pragma unroll
      for (int n2 = 0; n2 < 8; ++n2) {
        s8v bv = *(const s8v*)&Vl[n2 * 16 + ln][kv * 32 + quad * 8];
        o[n2] = __builtin_amdgcn_mfma_f32_16x16x32_bf16(ap, bv, o[n2], 0, 0, 0);
      }
    }
    __syncthreads();
  }

  // normalize + store fp32
  float inv[4];
#pragma unroll
  for (int r = 0; r < 4; ++r) inv[r] = 1.0f / lrow[r];
  float* Ob = out + ((size_t)b * L_Q + q0 + w * 16) * DIM;
#pragma unroll
  for (int n2 = 0; n2 < 8; ++n2)
#pragma unroll
    for (int r = 0; r < 4; ++r)
      Ob[(size_t)(quad * 4 + r) * DIM + n2 * 16 + ln] = o[n2][r] * inv[r];
}

extern "C" void kernel_launch(void* const* d_in, const int* in_sizes, int n_in,
                              void* d_out, int out_size, void* d_ws, size_t ws_size,
                              hipStream_t stream) {
  const float* query = (const float*)d_in[0];
  const float* key   = (const float*)d_in[1];
  const float* value = (const float*)d_in[2];
  const float* Wq    = (const float*)d_in[3];
  const float* Wk    = (const float*)d_in[4];
  const float* Wv    = (const float*)d_in[5];
  const int*   mask  = (const int*)d_in[6];
  float* out = (float*)d_out;

  u16* qp = (u16*)d_ws;
  u16* kp = qp + (size_t)B_N * L_Q * DIM;
  u16* vt = kp + (size_t)B_N * L_K * DIM;

  hipLaunchKernelGGL(proj_all, dim3(768), dim3(256), 0, stream,
                     query, key, value, Wq, Wk, Wv, qp, kp, vt);
  hipLaunchKernelGGL(flash, dim3(256), dim3(256), 0, stream,
                     qp, kp, vt, mask, out);
}

// Round 2
// 225.538 us; speedup vs baseline: 1.2064x; 1.2064x over previous
//
#include <hip/hip_runtime.h>

typedef unsigned short u16;
typedef __attribute__((ext_vector_type(8))) short s8v;   // 8 bf16 in 4 VGPRs
typedef __attribute__((ext_vector_type(4))) float f4v;   // MFMA accumulator

#define B_N 8
#define L_Q 2048
#define L_K 2048
#define DIM 128
#define KT  64
#define KSPLIT 4
#define KCHUNK (L_K / KSPLIT)   // 512 keys per split

__device__ __forceinline__ u16 f2bf(float f) {
  union { float f; unsigned u; } v; v.f = f;
  return (u16)((v.u + 0x7fffu + ((v.u >> 16) & 1u)) >> 16);  // RTN-even
}

// ---------------------------------------------------------------------------
// MFMA projections: q = X@Wq (scale*log2e folded into Wq), k = X@Wk,
// vt = (X@Wv)^T. bf16 inputs (cast on the fly), fp32 accumulate.
// grid 768 = which(3) x b(8) x rowtile(32 of 64 rows); block 256 (4 waves).
// ---------------------------------------------------------------------------
__global__ __launch_bounds__(256) void proj_mfma(
    const float* __restrict__ query, const float* __restrict__ key,
    const float* __restrict__ value, const float* __restrict__ Wq,
    const float* __restrict__ Wk, const float* __restrict__ Wv,
    u16* __restrict__ qp, u16* __restrict__ kp, u16* __restrict__ vt) {
  __shared__ __align__(16) u16 Wt[DIM][DIM + 8];   // W^T, bf16
  const int tid = threadIdx.x;
  const int bi = blockIdx.x;
  const int which = bi >> 8;           // 0=q 1=k 2=v
  const int sub = bi & 255;
  const int b = sub >> 5;
  const int rt = sub & 31;
  const float* X = (which == 0) ? query : (which == 1) ? key : value;
  const float* W = (which == 0) ? Wq : (which == 1) ? Wk : Wv;
  const float wscale = (which == 0) ? (1.44269504089f / 11.3137084990f) : 1.0f;

  // stage W^T (transposed, scaled, bf16)
#pragma unroll
  for (int i = 0; i < 16; ++i) {
    int f4i = tid + i * 256;                 // 4096 float4 chunks
    float4 w4 = *(const float4*)(W + f4i * 4);
    int row = f4i >> 5, col = (f4i & 31) * 4;
    Wt[col + 0][row] = f2bf(w4.x * wscale);
    Wt[col + 1][row] = f2bf(w4.y * wscale);
    Wt[col + 2][row] = f2bf(w4.z * wscale);
    Wt[col + 3][row] = f2bf(w4.w * wscale);
  }
  __syncthreads();

  const int w = tid >> 6, lane = tid & 63;
  const int ln = lane & 15, quad = lane >> 4;
  const int xrow = rt * 64 + w * 16 + ln;
  const float* Xr = X + ((size_t)b * L_Q + xrow) * DIM;

  // A fragments: A[m=ln][k=32ks+8quad+j], fp32 -> bf16
  s8v a[4];
#pragma unroll
  for (int ks = 0; ks < 4; ++ks) {
    float4 xa = *(const float4*)(Xr + ks * 32 + quad * 8);
    float4 xb = *(const float4*)(Xr + ks * 32 + quad * 8 + 4);
    s8v t;
    t[0] = (short)f2bf(xa.x); t[1] = (short)f2bf(xa.y);
    t[2] = (short)f2bf(xa.z); t[3] = (short)f2bf(xa.w);
    t[4] = (short)f2bf(xb.x); t[5] = (short)f2bf(xb.y);
    t[6] = (short)f2bf(xb.z); t[7] = (short)f2bf(xb.w);
    a[ks] = t;
  }

  f4v acc[8];
#pragma unroll
  for (int i = 0; i < 8; ++i) acc[i] = (f4v){0.f, 0.f, 0.f, 0.f};
#pragma unroll
  for (int ks = 0; ks < 4; ++ks)
#pragma unroll
    for (int nt = 0; nt < 8; ++nt) {
      s8v bw = *(const s8v*)&Wt[nt * 16 + ln][ks * 32 + quad * 8];
      acc[nt] = __builtin_amdgcn_mfma_f32_16x16x32_bf16(a[ks], bw, acc[nt], 0, 0, 0);
    }

  if (which < 2) {
    u16* Y = ((which == 0) ? qp : kp) + ((size_t)b * L_Q + rt * 64 + w * 16) * DIM;
#pragma unroll
    for (int nt = 0; nt < 8; ++nt)
#pragma unroll
      for (int r = 0; r < 4; ++r)
        Y[(size_t)(quad * 4 + r) * DIM + nt * 16 + ln] = f2bf(acc[nt][r]);
  } else {
    u16* Y = vt + (size_t)b * DIM * L_K;
    const int kb = rt * 64 + w * 16;
#pragma unroll
    for (int nt = 0; nt < 8; ++nt)
#pragma unroll
      for (int r = 0; r < 4; ++r)
        Y[(size_t)(nt * 16 + ln) * L_K + kb + quad * 4 + r] = f2bf(acc[nt][r]);
  }
}

// ---------------------------------------------------------------------------
// K-split flash: grid 2048 = b(8, XCD-local) x part(4) x qtile(64 of 32 rows),
// block 128 (2 waves x 16 q-rows). Each block does 512 keys (8 KT-iters),
// writes unnormalized O + (m,l) partials. LDS 40448B -> 4 blocks/CU.
// ---------------------------------------------------------------------------
__global__ __launch_bounds__(128) void flash_split(
    const u16* __restrict__ qp, const u16* __restrict__ kp,
    const u16* __restrict__ vt, const int* __restrict__ mask,
    float* __restrict__ po, float* __restrict__ ml) {
  __shared__ __align__(16) u16 Kl[KT][DIM + 8];     // [64][136] 17408B
  __shared__ __align__(16) u16 Vl[DIM][KT + 8];     // [128][72] 18432B
  __shared__ __align__(16) u16 Pl[2][16][KT + 8];   // per-wave P  4608B

  const int tid = threadIdx.x;
  const int bi = blockIdx.x;
  const int b = bi & 7;               // batch -> XCD
  const int rest = bi >> 3;
  const int p = rest & 3;             // K split
  const int qt = rest >> 2;           // 0..63
  const int q0 = qt * 32;
  const int w = tid >> 6;
  const int lane = tid & 63;
  const int ln = lane & 15;
  const int quad = lane >> 4;
  const int kbase = p * KCHUNK;

  const u16* Qb = qp + (size_t)b * L_Q * DIM;
  const u16* Kb = kp + (size_t)b * L_K * DIM;
  const u16* Vb = vt + (size_t)b * DIM * L_K;
  const int* mb = mask + b * L_K;

  s8v aq[4];
  const int qrow = q0 + w * 16 + ln;
#pragma unroll
  for (int ks = 0; ks < 4; ++ks)
    aq[ks] = *(const s8v*)(Qb + (size_t)qrow * DIM + ks * 32 + quad * 8);

  f4v o[8];
#pragma unroll
  for (int i = 0; i < 8; ++i) o[i] = (f4v){0.f, 0.f, 0.f, 0.f};
  float mrow[4] = {-__builtin_inff(), -__builtin_inff(), -__builtin_inff(), -__builtin_inff()};
  float lrow[4] = {0.f, 0.f, 0.f, 0.f};

  for (int it = 0; it < KCHUNK / KT; ++it) {
    const int k0 = kbase + it * KT;
#pragma unroll
    for (int r = 0; r < 8; ++r) {      // K tile: 1024 chunks / 128 thr
      int c16 = tid + r * 128;
      int row = c16 >> 4, cc = (c16 & 15) * 8;
      *(s8v*)&Kl[row][cc] = *(const s8v*)(Kb + (size_t)(k0 + row) * DIM + cc);
    }
#pragma unroll
    for (int r = 0; r < 8; ++r) {      // V^T tile
      int c16 = tid + r * 128;
      int row = c16 >> 3, cc = (c16 & 7) * 8;
      *(s8v*)&Vl[row][cc] = *(const s8v*)(Vb + (size_t)row * L_K + k0 + cc);
    }
    __syncthreads();

    f4v s[4];
#pragma unroll
    for (int nt = 0; nt < 4; ++nt) s[nt] = (f4v){0.f, 0.f, 0.f, 0.f};
#pragma unroll
    for (int ks = 0; ks < 4; ++ks)
#pragma unroll
      for (int nt = 0; nt < 4; ++nt) {
        s8v bk = *(const s8v*)&Kl[nt * 16 + ln][ks * 32 + quad * 8];
        s[nt] = __builtin_amdgcn_mfma_f32_16x16x32_bf16(aq[ks], bk, s[nt], 0, 0, 0);
      }
#pragma unroll
    for (int nt = 0; nt < 4; ++nt) {
      if (mb[k0 + nt * 16 + ln] == 0) {
        s[nt][0] = -__builtin_inff(); s[nt][1] = -__builtin_inff();
        s[nt][2] = -__builtin_inff(); s[nt][3] = -__builtin_inff();
      }
    }
    float rmax[4];
#pragma unroll
    for (int r = 0; r < 4; ++r)
      rmax[r] = fmaxf(fmaxf(s[0][r], s[1][r]), fmaxf(s[2][r], s[3][r]));
#pragma unroll
    for (int off = 8; off >= 1; off >>= 1)
#pragma unroll
      for (int r = 0; r < 4; ++r)
        rmax[r] = fmaxf(rmax[r], __shfl_xor(rmax[r], off, 64));

    float alpha[4];
#pragma unroll
    for (int r = 0; r < 4; ++r) {
      float mn = fmaxf(mrow[r], rmax[r]);
      alpha[r] = exp2f(mrow[r] - mn);
      mrow[r] = mn;
    }
#pragma unroll
    for (int nt = 0; nt < 4; ++nt)
#pragma unroll
      for (int r = 0; r < 4; ++r) s[nt][r] = exp2f(s[nt][r] - mrow[r]);
    float rsum[4];
#pragma unroll
    for (int r = 0; r < 4; ++r)
      rsum[r] = (s[0][r] + s[1][r]) + (s[2][r] + s[3][r]);
#pragma unroll
    for (int off = 8; off >= 1; off >>= 1)
#pragma unroll
      for (int r = 0; r < 4; ++r) rsum[r] += __shfl_xor(rsum[r], off, 64);
#pragma unroll
    for (int r = 0; r < 4; ++r) lrow[r] = lrow[r] * alpha[r] + rsum[r];

#pragma unroll
    for (int nt = 0; nt < 4; ++nt)
#pragma unroll
      for (int r = 0; r < 4; ++r)
        Pl[w][quad * 4 + r][nt * 16 + ln] = f2bf(s[nt][r]);

#pragma unroll
    for (int n2 = 0; n2 < 8; ++n2)
#pragma unroll
      for (int r = 0; r < 4; ++r) o[n2][r] *= alpha[r];

#pragma unroll
    for (int kv = 0; kv < 2; ++kv) {
      s8v ap = *(const s8v*)&Pl[w][ln][kv * 32 + quad * 8];
#pragma unroll
      for (int n2 = 0; n2 < 8; ++n2) {
        s8v bv = *(const s8v*)&Vl[n2 * 16 + ln][kv * 32 + quad * 8];
        o[n2] = __builtin_amdgcn_mfma_f32_16x16x32_bf16(ap, bv, o[n2], 0, 0, 0);
      }
    }
    __syncthreads();
  }

  // write partials (unnormalized O, m, l)
#pragma unroll
  for (int n2 = 0; n2 < 8; ++n2)
#pragma unroll
    for (int r = 0; r < 4; ++r) {
      size_t q = (size_t)b * L_Q + q0 + w * 16 + quad * 4 + r;
      po[(q * KSPLIT + p) * DIM + n2 * 16 + ln] = o[n2][r];
    }
  if (ln == 0) {
#pragma unroll
    for (int r = 0; r < 4; ++r) {
      size_t q = (size_t)b * L_Q + q0 + w * 16 + quad * 4 + r;
      ml[(q * KSPLIT + p) * 2 + 0] = mrow[r];
      ml[(q * KSPLIT + p) * 2 + 1] = lrow[r];
    }
  }
}

// ---------------------------------------------------------------------------
// Combine splits: out[q] = sum_p 2^(m_p-M) * O_p / sum_p l_p 2^(m_p-M)
// grid 2048 x 256 threads; 8 rows/block, 32 threads/row (float4 per thread).
// ---------------------------------------------------------------------------
__global__ __launch_bounds__(256) void combine(
    const float* __restrict__ po, const float* __restrict__ ml,
    float* __restrict__ out) {
  const int t = threadIdx.x;
  const int lr = t >> 5, l32 = t & 31;
  const size_t q = (size_t)blockIdx.x * 8 + lr;

  float m[KSPLIT], l[KSPLIT];
#pragma unroll
  for (int p = 0; p < KSPLIT; ++p) {
    m[p] = ml[(q * KSPLIT + p) * 2 + 0];
    l[p] = ml[(q * KSPLIT + p) * 2 + 1];
  }
  float M = fmaxf(fmaxf(m[0], m[1]), fmaxf(m[2], m[3]));
  float wp[KSPLIT], L = 0.f;
#pragma unroll
  for (int p = 0; p < KSPLIT; ++p) { wp[p] = exp2f(m[p] - M); L += l[p] * wp[p]; }
  float invL = 1.0f / L;

  float4 acc = make_float4(0.f, 0.f, 0.f, 0.f);
#pragma unroll
  for (int p = 0; p < KSPLIT; ++p) {
    float4 v = *(const float4*)(po + (q * KSPLIT + p) * DIM + l32 * 4);
    acc.x += wp[p] * v.x; acc.y += wp[p] * v.y;
    acc.z += wp[p] * v.z; acc.w += wp[p] * v.w;
  }
  acc.x *= invL; acc.y *= invL; acc.z *= invL; acc.w *= invL;
  *(float4*)(out + q * DIM + l32 * 4) = acc;
}

extern "C" void kernel_launch(void* const* d_in, const int* in_sizes, int n_in,
                              void* d_out, int out_size, void* d_ws, size_t ws_size,
                              hipStream_t stream) {
  const float* query = (const float*)d_in[0];
  const float* key   = (const float*)d_in[1];
  const float* value = (const float*)d_in[2];
  const float* Wq    = (const float*)d_in[3];
  const float* Wk    = (const float*)d_in[4];
  const float* Wv    = (const float*)d_in[5];
  const int*   mask  = (const int*)d_in[6];
  float* out = (float*)d_out;

  u16* qp = (u16*)d_ws;
  u16* kp = qp + (size_t)B_N * L_Q * DIM;
  u16* vt = kp + (size_t)B_N * L_K * DIM;
  float* po = (float*)(vt + (size_t)B_N * DIM * L_K);               // 33.5 MB
  float* ml = po + (size_t)B_N * L_Q * KSPLIT * DIM;                // 0.5 MB

  hipLaunchKernelGGL(proj_mfma, dim3(768), dim3(256), 0, stream,
                     query, key, value, Wq, Wk, Wv, qp, kp, vt);
  hipLaunchKernelGGL(flash_split, dim3(2048), dim3(128), 0, stream,
                     qp, kp, vt, mask, po, ml);
  hipLaunchKernelGGL(combine, dim3((B_N * L_Q) / 8), dim3(256), 0, stream,
                     po, ml, out);
}

// Round 4
// 141.679 us; speedup vs baseline: 1.9204x; 1.5919x over previous
//
#include <hip/hip_runtime.h>
#include <hip/hip_bf16.h>

typedef unsigned short u16;
typedef unsigned int u32;
typedef __attribute__((ext_vector_type(8))) short s8v;   // 8 bf16 in 4 VGPRs
typedef __attribute__((ext_vector_type(4))) float f4v;   // MFMA accumulator

#define B_N 8
#define L_Q 2048
#define L_K 2048
#define DIM 128
#define KT  64
#define KSPLIT 4
#define KCHUNK (L_K / KSPLIT)   // 512 keys per split

__device__ __forceinline__ u16 f2bf(float f) {
  union { float f; unsigned u; } v; v.f = f;
  return (u16)((v.u + 0x7fffu + ((v.u >> 16) & 1u)) >> 16);  // RTN-even
}
__device__ __forceinline__ u32 packbf2(float a, float b) {
  union { __hip_bfloat162 h; u32 u; } v;
  v.h = __float22bfloat162_rn(make_float2(a, b));
  return v.u;
}

// ---------------------------------------------------------------------------
// MFMA projections. q = X@Wq (scale*log2e folded), k = X@Wk, vt = (X@Wv)^T.
// V output goes through an LDS transpose so global stores are coalesced.
// grid 768 = which(3) x b(8) x rowtile(32 of 64 rows); block 256 (4 waves).
// ---------------------------------------------------------------------------
__global__ __launch_bounds__(256) void proj_mfma(
    const float* __restrict__ query, const float* __restrict__ key,
    const float* __restrict__ value, const float* __restrict__ Wq,
    const float* __restrict__ Wk, const float* __restrict__ Wv,
    u16* __restrict__ qp, u16* __restrict__ kp, u16* __restrict__ vt) {
  __shared__ __align__(16) u16 Wt[DIM][DIM + 8];    // W^T bf16, 34816B
  __shared__ __align__(16) u16 Vt[DIM][KT + 8];     // V^T out tile, 18432B
  const int tid = threadIdx.x;
  const int bi = blockIdx.x;
  const int which = bi >> 8;           // 0=q 1=k 2=v
  const int sub = bi & 255;
  const int b = sub >> 5;
  const int rt = sub & 31;
  const float* X = (which == 0) ? query : (which == 1) ? key : value;
  const float* W = (which == 0) ? Wq : (which == 1) ? Wk : Wv;
  const float wscale = (which == 0) ? (1.44269504089f / 11.3137084990f) : 1.0f;

#pragma unroll
  for (int i = 0; i < 16; ++i) {
    int f4i = tid + i * 256;                 // 4096 float4 chunks of W
    float4 w4 = *(const float4*)(W + f4i * 4);
    int row = f4i >> 5, col = (f4i & 31) * 4;
    Wt[col + 0][row] = f2bf(w4.x * wscale);
    Wt[col + 1][row] = f2bf(w4.y * wscale);
    Wt[col + 2][row] = f2bf(w4.z * wscale);
    Wt[col + 3][row] = f2bf(w4.w * wscale);
  }
  __syncthreads();

  const int w = tid >> 6, lane = tid & 63;
  const int ln = lane & 15, quad = lane >> 4;
  const int xrow = rt * 64 + w * 16 + ln;
  const float* Xr = X + ((size_t)b * L_Q + xrow) * DIM;

  s8v a[4];
#pragma unroll
  for (int ks = 0; ks < 4; ++ks) {
    float4 xa = *(const float4*)(Xr + ks * 32 + quad * 8);
    float4 xb = *(const float4*)(Xr + ks * 32 + quad * 8 + 4);
    s8v t;
    t[0] = (short)f2bf(xa.x); t[1] = (short)f2bf(xa.y);
    t[2] = (short)f2bf(xa.z); t[3] = (short)f2bf(xa.w);
    t[4] = (short)f2bf(xb.x); t[5] = (short)f2bf(xb.y);
    t[6] = (short)f2bf(xb.z); t[7] = (short)f2bf(xb.w);
    a[ks] = t;
  }

  f4v acc[8];
#pragma unroll
  for (int i = 0; i < 8; ++i) acc[i] = (f4v){0.f, 0.f, 0.f, 0.f};
#pragma unroll
  for (int ks = 0; ks < 4; ++ks)
#pragma unroll
    for (int nt = 0; nt < 8; ++nt) {
      s8v bw = *(const s8v*)&Wt[nt * 16 + ln][ks * 32 + quad * 8];
      acc[nt] = __builtin_amdgcn_mfma_f32_16x16x32_bf16(a[ks], bw, acc[nt], 0, 0, 0);
    }

  if (which < 2) {
    u16* Y = ((which == 0) ? qp : kp) + ((size_t)b * L_Q + rt * 64 + w * 16) * DIM;
#pragma unroll
    for (int nt = 0; nt < 8; ++nt)
#pragma unroll
      for (int r = 0; r < 4; ++r)
        Y[(size_t)(quad * 4 + r) * DIM + nt * 16 + ln] = f2bf(acc[nt][r]);
  } else {
    // write C tile transposed into LDS: Vt[dv][local_key]
#pragma unroll
    for (int nt = 0; nt < 8; ++nt) {
      *(u32*)&Vt[nt * 16 + ln][w * 16 + quad * 4]     = packbf2(acc[nt][0], acc[nt][1]);
      *(u32*)&Vt[nt * 16 + ln][w * 16 + quad * 4 + 2] = packbf2(acc[nt][2], acc[nt][3]);
    }
    __syncthreads();
    u16* Y = vt + (size_t)b * DIM * L_K;
#pragma unroll
    for (int r = 0; r < 4; ++r) {
      int c = tid + r * 256;                 // 1024 16B chunks
      int row = c >> 3, cc = (c & 7) * 8;
      *(s8v*)(Y + (size_t)row * L_K + rt * 64 + cc) = *(const s8v*)&Vt[row][cc];
    }
  }
}

// ---------------------------------------------------------------------------
// K-split flash, S^T formulation. grid 1024 = b(8) x part(4) x qtile(32 of
// 64 rows); block 256 (4 waves x 16 q-rows). Computes S^T = K·Q^T so softmax
// reduces in-lane (+2 shfls); P round-trips LDS (overlaid on K tile) back to
// the standard A-layout for PV. 36KB LDS -> 4 blocks/CU = 16 waves/CU.
// ---------------------------------------------------------------------------
__global__ __launch_bounds__(256, 4) void flash_split(
    const u16* __restrict__ qp, const u16* __restrict__ kp,
    const u16* __restrict__ vt, const int* __restrict__ mask,
    float* __restrict__ po, float* __restrict__ ml) {
  __shared__ __align__(16) u16 Kl[KT][DIM + 8];     // [64][136] 17408B (P overlays)
  __shared__ __align__(16) u16 Vl[DIM][KT + 8];     // [128][72] 18432B
  __shared__ float biasl[KT];                       // 256B

  const int tid = threadIdx.x;
  const int bi = blockIdx.x;
  const int b = bi & 7;               // batch -> XCD
  const int rest = bi >> 3;
  const int p = rest & 3;             // K split
  const int q0 = (rest >> 2) * 64;    // q tile base
  const int w = tid >> 6;
  const int lane = tid & 63;
  const int ln = lane & 15;
  const int quad = lane >> 4;
  const int kbase = p * KCHUNK;

  const u16* Qb = qp + (size_t)b * L_Q * DIM;
  const u16* Kb = kp + (size_t)b * L_K * DIM;
  const u16* Vb = vt + (size_t)b * DIM * L_K;
  const int* mb = mask + b * L_K;
  u16* Pw = ((u16*)Kl) + w * (16 * 72);   // per-wave P carve inside K tile

  // Q fragment (lane ln holds q-row q0+16w+ln); works as both A and B operand
  s8v aq[4];
  const int qrow = q0 + w * 16 + ln;
#pragma unroll
  for (int ks = 0; ks < 4; ++ks)
    aq[ks] = *(const s8v*)(Qb + (size_t)qrow * DIM + ks * 32 + quad * 8);

  f4v o[8];
#pragma unroll
  for (int i = 0; i < 8; ++i) o[i] = (f4v){0.f, 0.f, 0.f, 0.f};
  float mrow = -__builtin_inff();
  float lrow = 0.f;

  for (int it = 0; it < KCHUNK / KT; ++it) {
    const int k0 = kbase + it * KT;
#pragma unroll
    for (int r = 0; r < 4; ++r) {      // K tile [64][128]: 1024 chunks
      int c16 = tid + r * 256;
      int row = c16 >> 4, cc = (c16 & 15) * 8;
      *(s8v*)&Kl[row][cc] = *(const s8v*)(Kb + (size_t)(k0 + row) * DIM + cc);
    }
#pragma unroll
    for (int r = 0; r < 4; ++r) {      // V^T tile [128][64]
      int c16 = tid + r * 256;
      int row = c16 >> 3, cc = (c16 & 7) * 8;
      *(s8v*)&Vl[row][cc] = *(const s8v*)(Vb + (size_t)row * L_K + k0 + cc);
    }
    if (tid < KT) biasl[tid] = (mb[k0 + tid] == 0) ? -__builtin_inff() : 0.f;
    __syncthreads();

    // S^T = K · Q^T : A = K-frag, B = Q-frag.
    // C[row=quad*4+r][col=ln] = S^T[key=mt*16+quad*4+r][qrow=ln]
    f4v s[4];
#pragma unroll
    for (int mt = 0; mt < 4; ++mt) s[mt] = (f4v){0.f, 0.f, 0.f, 0.f};
#pragma unroll
    for (int ks = 0; ks < 4; ++ks)
#pragma unroll
      for (int mt = 0; mt < 4; ++mt) {
        s8v bk = *(const s8v*)&Kl[mt * 16 + ln][ks * 32 + quad * 8];
        s[mt] = __builtin_amdgcn_mfma_f32_16x16x32_bf16(bk, aq[ks], s[mt], 0, 0, 0);
      }
    // additive mask bias (per key = per reg)
#pragma unroll
    for (int mt = 0; mt < 4; ++mt) {
      float4 bt = *(const float4*)&biasl[mt * 16 + quad * 4];
      s[mt][0] += bt.x; s[mt][1] += bt.y; s[mt][2] += bt.z; s[mt][3] += bt.w;
    }
    // row (=lane) max over 64 keys: 15 in-lane + 2 shfl
    // (lane (ln,quad) holds keys {mt*16+quad*4+r} — quads are DISJOINT subsets)
    float m16 = s[0][0];
#pragma unroll
    for (int mt = 0; mt < 4; ++mt)
#pragma unroll
      for (int r = 0; r < 4; ++r) m16 = fmaxf(m16, s[mt][r]);
    m16 = fmaxf(m16, __shfl_xor(m16, 16, 64));
    m16 = fmaxf(m16, __shfl_xor(m16, 32, 64));

    float mn = fmaxf(mrow, m16);
    float alpha = exp2f(fminf(mrow - mn, 0.f));   // guards -inf - -inf
    mrow = mn;
    // p = 2^(s-m), in-lane row sum
    float rs = 0.f;
#pragma unroll
    for (int mt = 0; mt < 4; ++mt)
#pragma unroll
      for (int r = 0; r < 4; ++r) {
        s[mt][r] = exp2f(fminf(s[mt][r] - mn, 0.f));
        rs += s[mt][r];
      }
    rs += __shfl_xor(rs, 16, 64);
    rs += __shfl_xor(rs, 32, 64);
    lrow = lrow * alpha + rs;   // rs is the exact 64-key row sum (disjoint quads)

    __syncthreads();   // all QK reads of Kl done before P overlays it

    // P[qrow][key] into LDS (packed pairs: r=0,1 and r=2,3 are adjacent keys)
#pragma unroll
    for (int mt = 0; mt < 4; ++mt) {
      *(u32*)(Pw + ln * 72 + mt * 16 + quad * 4)     = packbf2(s[mt][0], s[mt][1]);
      *(u32*)(Pw + ln * 72 + mt * 16 + quad * 4 + 2) = packbf2(s[mt][2], s[mt][3]);
    }

    // rescale O: alpha is per-lane(row ln); O rows are quad*4+r -> broadcast
    float ar[4];
#pragma unroll
    for (int r = 0; r < 4; ++r) ar[r] = __shfl(alpha, quad * 4 + r, 64);
#pragma unroll
    for (int n2 = 0; n2 < 8; ++n2)
#pragma unroll
      for (int r = 0; r < 4; ++r) o[n2][r] *= ar[r];

    // O += P V : A = P-frag (own wave's LDS), B = V^T-frag
#pragma unroll
    for (int kv = 0; kv < 2; ++kv) {
      s8v ap = *(const s8v*)(Pw + ln * 72 + kv * 32 + quad * 8);
#pragma unroll
      for (int n2 = 0; n2 < 8; ++n2) {
        s8v bv = *(const s8v*)&Vl[n2 * 16 + ln][kv * 32 + quad * 8];
        o[n2] = __builtin_amdgcn_mfma_f32_16x16x32_bf16(ap, bv, o[n2], 0, 0, 0);
      }
    }
    __syncthreads();   // protect K/V/bias restage (and P region)
  }

  // write partials: unnormalized O (C-layout rows quad*4+r), per-row (m,l)
#pragma unroll
  for (int n2 = 0; n2 < 8; ++n2)
#pragma unroll
    for (int r = 0; r < 4; ++r) {
      size_t q = (size_t)b * L_Q + q0 + w * 16 + quad * 4 + r;
      po[(q * KSPLIT + p) * DIM + n2 * 16 + ln] = o[n2][r];
    }
  if (quad == 0) {
    size_t q = (size_t)b * L_Q + q0 + w * 16 + ln;
    *(float2*)&ml[(q * KSPLIT + p) * 2] = make_float2(mrow, lrow);
  }
}

// ---------------------------------------------------------------------------
// Combine splits: out[q] = sum_p 2^(m_p-M) O_p / sum_p l_p 2^(m_p-M)
// ---------------------------------------------------------------------------
__global__ __launch_bounds__(256) void combine(
    const float* __restrict__ po, const float* __restrict__ ml,
    float* __restrict__ out) {
  const int t = threadIdx.x;
  const int lr = t >> 5, l32 = t & 31;
  const size_t q = (size_t)blockIdx.x * 8 + lr;

  float m[KSPLIT], l[KSPLIT];
#pragma unroll
  for (int p = 0; p < KSPLIT; ++p) {
    m[p] = ml[(q * KSPLIT + p) * 2 + 0];
    l[p] = ml[(q * KSPLIT + p) * 2 + 1];
  }
  float M = m[0];
#pragma unroll
  for (int p = 1; p < KSPLIT; ++p) M = fmaxf(M, m[p]);
  float wp[KSPLIT], L = 0.f;
#pragma unroll
  for (int p = 0; p < KSPLIT; ++p) {
    wp[p] = exp2f(fminf(m[p] - M, 0.f));
    L += l[p] * wp[p];
  }
  float invL = 1.0f / L;

  float4 acc = make_float4(0.f, 0.f, 0.f, 0.f);
#pragma unroll
  for (int p = 0; p < KSPLIT; ++p) {
    float4 v = *(const float4*)(po + (q * KSPLIT + p) * DIM + l32 * 4);
    acc.x += wp[p] * v.x; acc.y += wp[p] * v.y;
    acc.z += wp[p] * v.z; acc.w += wp[p] * v.w;
  }
  acc.x *= invL; acc.y *= invL; acc.z *= invL; acc.w *= invL;
  *(float4*)(out + q * DIM + l32 * 4) = acc;
}

extern "C" void kernel_launch(void* const* d_in, const int* in_sizes, int n_in,
                              void* d_out, int out_size, void* d_ws, size_t ws_size,
                              hipStream_t stream) {
  const float* query = (const float*)d_in[0];
  const float* key   = (const float*)d_in[1];
  const float* value = (const float*)d_in[2];
  const float* Wq    = (const float*)d_in[3];
  const float* Wk    = (const float*)d_in[4];
  const float* Wv    = (const float*)d_in[5];
  const int*   mask  = (const int*)d_in[6];
  float* out = (float*)d_out;

  u16* qp = (u16*)d_ws;
  u16* kp = qp + (size_t)B_N * L_Q * DIM;
  u16* vt = kp + (size_t)B_N * L_K * DIM;
  float* po = (float*)(vt + (size_t)B_N * DIM * L_K);   // 33.5 MB
  float* ml = po + (size_t)B_N * L_Q * KSPLIT * DIM;    // 0.5 MB

  hipLaunchKernelGGL(proj_mfma, dim3(768), dim3(256), 0, stream,
                     query, key, value, Wq, Wk, Wv, qp, kp, vt);
  hipLaunchKernelGGL(flash_split, dim3(1024), dim3(256), 0, stream,
                     qp, kp, vt, mask, po, ml);
  hipLaunchKernelGGL(combine, dim3((B_N * L_Q) / 8), dim3(256), 0, stream,
                     po, ml, out);
}

// Round 5
// 121.223 us; speedup vs baseline: 2.2445x; 1.1688x over previous
//
#include <hip/hip_runtime.h>
#include <hip/hip_bf16.h>

typedef unsigned short u16;
typedef unsigned int u32;
typedef __attribute__((ext_vector_type(8))) short s8v;   // 8 bf16 in 4 VGPRs
typedef __attribute__((ext_vector_type(4))) float f4v;   // MFMA accumulator

#define B_N 8
#define L_Q 2048
#define L_K 2048
#define DIM 128
#define KT  64
#define KSPLIT 4
#define KCHUNK (L_K / KSPLIT)   // 512 keys per split

__device__ __forceinline__ u16 f2bf(float f) {
  union { float f; unsigned u; } v; v.f = f;
  return (u16)((v.u + 0x7fffu + ((v.u >> 16) & 1u)) >> 16);  // RTN-even
}
__device__ __forceinline__ u32 packbf2(float a, float b) {
  union { __hip_bfloat162 h; u32 u; } v;
  v.h = __float22bfloat162_rn(make_float2(a, b));
  return v.u;
}
// async global->LDS, 16B per lane. LDS dest = wave-uniform base + lane*16.
__device__ __forceinline__ void async16(const u16* g, u16* l) {
  __builtin_amdgcn_global_load_lds(
      (const __attribute__((address_space(1))) u32*)(const void*)g,
      (__attribute__((address_space(3))) u32*)(void*)l, 16, 0, 0);
}

// ===========================================================================
// Fragment-order layouts (lane = quad*16+ln; each frag = 64 lanes x 8 u16):
//  qp: [b][qt(128 tiles of 16 q-rows)][ks(4)][lane][j]   frag: Q[qt*16+ln][ks*32+quad*8+j]
//  kp: [b][kt(32 tiles of 64 keys)][ks*4+mt][lane][j]    frag: K[kt*64+mt*16+ln][ks*32+quad*8+j]
//  vp: [b][kt(32)][kv*8+n2][lane][j]                     frag: V[kt*64+kv*32+quad*8+j][n2*16+ln]
// ===========================================================================

// ---------------------------------------------------------------------------
// MFMA projections -> fragment-order outputs. grid 768 = which(3) x b(8) x
// rowtile(32 of 64 rows); block 256 (4 waves x 16 rows).
// ---------------------------------------------------------------------------
__global__ __launch_bounds__(256) void proj_mfma(
    const float* __restrict__ query, const float* __restrict__ key,
    const float* __restrict__ value, const float* __restrict__ Wq,
    const float* __restrict__ Wk, const float* __restrict__ Wv,
    u16* __restrict__ qp, u16* __restrict__ kp, u16* __restrict__ vp) {
  __shared__ __align__(16) u16 Wf[32 * 520];   // W^T frags, stride 520 u16 (pad vs conflicts)
  __shared__ __align__(16) u16 Fb[8192];       // output frag staging, 16KB
  const int tid = threadIdx.x;
  const int bi = blockIdx.x;
  const int which = bi >> 8;           // 0=q 1=k 2=v
  const int sub = bi & 255;
  const int b = sub >> 5;
  const int rt = sub & 31;
  const float* X = (which == 0) ? query : (which == 1) ? key : value;
  const float* W = (which == 0) ? Wq : (which == 1) ? Wk : Wv;
  const float wscale = (which == 0) ? (1.44269504089f / 11.3137084990f) : 1.0f;

  // stage W^T into fragment order: element (k,n) -> frag(ks=k>>5, nt=n>>4),
  // lane''=((k&31)>>3)*16 + (n&15), j=k&7
#pragma unroll
  for (int i = 0; i < 16; ++i) {
    int f4i = tid + i * 256;                 // 4096 float4 chunks of W
    float4 w4 = *(const float4*)(W + f4i * 4);
    int k = f4i >> 5, col = (f4i & 31) * 4;
    int ks = k >> 5, qd = (k & 31) >> 3, j = k & 7;
    float wv[4] = {w4.x, w4.y, w4.z, w4.w};
#pragma unroll
    for (int c = 0; c < 4; ++c) {
      int n = col + c;
      Wf[(ks * 8 + (n >> 4)) * 520 + (qd * 16 + (n & 15)) * 8 + j] = f2bf(wv[c] * wscale);
    }
  }
  __syncthreads();

  const int w = tid >> 6, lane = tid & 63;
  const int ln = lane & 15, quad = lane >> 4;
  const int xrow = rt * 64 + w * 16 + ln;
  const float* Xr = X + ((size_t)b * L_Q + xrow) * DIM;

  s8v a[4];
#pragma unroll
  for (int ks = 0; ks < 4; ++ks) {
    float4 xa = *(const float4*)(Xr + ks * 32 + quad * 8);
    float4 xb = *(const float4*)(Xr + ks * 32 + quad * 8 + 4);
    s8v t;
    t[0] = (short)f2bf(xa.x); t[1] = (short)f2bf(xa.y);
    t[2] = (short)f2bf(xa.z); t[3] = (short)f2bf(xa.w);
    t[4] = (short)f2bf(xb.x); t[5] = (short)f2bf(xb.y);
    t[6] = (short)f2bf(xb.z); t[7] = (short)f2bf(xb.w);
    a[ks] = t;
  }

  f4v acc[8];
#pragma unroll
  for (int i = 0; i < 8; ++i) acc[i] = (f4v){0.f, 0.f, 0.f, 0.f};
  const u16* Wl0 = Wf + lane * 8;
#pragma unroll
  for (int ks = 0; ks < 4; ++ks)
#pragma unroll
    for (int nt = 0; nt < 8; ++nt) {
      s8v bw = *(const s8v*)(Wl0 + (ks * 8 + nt) * 520);
      acc[nt] = __builtin_amdgcn_mfma_f32_16x16x32_bf16(a[ks], bw, acc[nt], 0, 0, 0);
    }

  // epilogue: C(lane(ln,quad), acc[nt][r]) = Y[row=w*16+quad*4+r][d=nt*16+ln]
  // -> fragment-order staging in Fb, then linear coalesced copy to global.
  if (which < 2) {
#pragma unroll
    for (int nt = 0; nt < 8; ++nt) {
      int ks = nt >> 1;
      int f = (which == 0) ? (w * 4 + ks) : (ks * 4 + w);
      int lp = ((nt & 1) * 2 + (ln >> 3)) * 16;   // + (quad*4+r)
      int j = ln & 7;
#pragma unroll
      for (int r = 0; r < 4; ++r)
        Fb[f * 512 + (lp + quad * 4 + r) * 8 + j] = f2bf(acc[nt][r]);
    }
  } else {
#pragma unroll
    for (int nt = 0; nt < 8; ++nt) {
      int f = (w >> 1) * 8 + nt;
      int lp = ((w & 1) * 2 + (quad >> 1)) * 16 + ln;
      int jb = (quad & 1) * 4;
#pragma unroll
      for (int r = 0; r < 4; ++r)
        Fb[f * 512 + lp * 8 + jb + r] = f2bf(acc[nt][r]);
    }
  }
  __syncthreads();

  u16* Y = (which == 0) ? qp + (size_t)(b * 512 + rt * 16) * 512
         : (which == 1) ? kp + (size_t)((b * 32 + rt) * 16) * 512
                        : vp + (size_t)((b * 32 + rt) * 16) * 512;
#pragma unroll
  for (int r = 0; r < 4; ++r) {
    int c = tid + r * 256;                 // 1024 16B chunks, identity copy
    *(s8v*)(Y + c * 8) = *(const s8v*)(Fb + c * 8);
  }
}

// ---------------------------------------------------------------------------
// K-split flash, S^T formulation, fragment-native LDS.
// grid 1024 = b(8) x part(4) x qblock(32 of 64 rows); block 256 (4 waves).
// LDS: Kf 16KB + Vf 16KB + bias 256B -> 4 blocks/CU. P overlays Kf[0:8KB].
// ---------------------------------------------------------------------------
__global__ __launch_bounds__(256, 4) void flash_split(
    const u16* __restrict__ qp, const u16* __restrict__ kp,
    const u16* __restrict__ vp, const int* __restrict__ mask,
    float* __restrict__ po, float* __restrict__ ml) {
  __shared__ __align__(16) u16 Kf[8192];   // 16 frags x 1KB
  __shared__ __align__(16) u16 Vf[8192];
  __shared__ float biasl[KT];

  const int tid = threadIdx.x;
  const int bi = blockIdx.x;
  const int b = bi & 7;               // batch -> XCD
  const int rest = bi >> 3;
  const int p = rest & 3;             // K split
  const int qb = rest >> 2;           // 0..31 (64 q-rows each)
  const int w = tid >> 6;
  const int lane = tid & 63;
  const int ln = lane & 15;
  const int quad = lane >> 4;

  const int* mb = mask + b * L_K;

  // Q fragments: qtile = qb*4 + w
  const u16* Qt = qp + ((size_t)(b * 128 + qb * 4 + w) * 4) * 512;
  s8v aq[4];
#pragma unroll
  for (int ks = 0; ks < 4; ++ks)
    aq[ks] = *(const s8v*)(Qt + ks * 512 + lane * 8);

  f4v o[8];
#pragma unroll
  for (int i = 0; i < 8; ++i) o[i] = (f4v){0.f, 0.f, 0.f, 0.f};
  float mrow = -__builtin_inff();
  float lrow = 0.f;

  const u16* Kl0 = Kf + lane * 8;
  const u16* Vl0 = Vf + lane * 8;
  u16* Pw = Kf + w * 1024;             // per-wave P region (2KB), overlays Kf
  const u16* Pl0 = Pw + lane * 8;

  for (int it = 0; it < KCHUNK / KT; ++it) {
    const int kt = p * (KCHUNK / KT) + it;
    const int k0 = kt * KT;
    const u16* Ktile = kp + (size_t)((b * 32 + kt) * 16) * 512;
    const u16* Vtile = vp + (size_t)((b * 32 + kt) * 16) * 512;
    // stage: 16KB each, wave w copies chunk groups w*4+c (64 lanes x 16B)
#pragma unroll
    for (int c = 0; c < 4; ++c) {
      int cg = w * 4 + c;
      async16(Ktile + (size_t)(cg * 64 + lane) * 8, Kf + cg * 512);
      async16(Vtile + (size_t)(cg * 64 + lane) * 8, Vf + cg * 512);
    }
    int mv = mb[k0 + lane];
    bool allones = (__ballot(mv != 0) == ~0ull);
    if (!allones && tid < KT) biasl[tid] = (mv == 0) ? -__builtin_inff() : 0.f;
    __syncthreads();

    // S^T = K·Q^T: C[key=mt*16+quad*4+r][qrow=ln]
    f4v s[4];
#pragma unroll
    for (int mt = 0; mt < 4; ++mt) s[mt] = (f4v){0.f, 0.f, 0.f, 0.f};
#pragma unroll
    for (int ks = 0; ks < 4; ++ks)
#pragma unroll
      for (int mt = 0; mt < 4; ++mt) {
        s8v bk = *(const s8v*)(Kl0 + (ks * 4 + mt) * 512);
        s[mt] = __builtin_amdgcn_mfma_f32_16x16x32_bf16(bk, aq[ks], s[mt], 0, 0, 0);
      }
    if (!allones) {
#pragma unroll
      for (int mt = 0; mt < 4; ++mt) {
        float4 bt = *(const float4*)&biasl[mt * 16 + quad * 4];
        s[mt][0] += bt.x; s[mt][1] += bt.y; s[mt][2] += bt.z; s[mt][3] += bt.w;
      }
    }
    // per-qrow (=lane) max over its 16 keys, then quads (disjoint) via 2 shfl
    float m16 = s[0][0];
#pragma unroll
    for (int mt = 0; mt < 4; ++mt)
#pragma unroll
      for (int r = 0; r < 4; ++r) m16 = fmaxf(m16, s[mt][r]);
    m16 = fmaxf(m16, __shfl_xor(m16, 16, 64));
    m16 = fmaxf(m16, __shfl_xor(m16, 32, 64));

    float mn = fmaxf(mrow, m16);
    float alpha = __builtin_amdgcn_exp2f(fminf(mrow - mn, 0.f));
    mrow = mn;
    float rs = 0.f;
#pragma unroll
    for (int mt = 0; mt < 4; ++mt)
#pragma unroll
      for (int r = 0; r < 4; ++r) {
        s[mt][r] = __builtin_amdgcn_exp2f(fminf(s[mt][r] - mn, 0.f));
        rs += s[mt][r];
      }
    rs += __shfl_xor(rs, 16, 64);
    rs += __shfl_xor(rs, 32, 64);
    lrow = lrow * alpha + rs;          // exact 64-key row sum (disjoint quads)

    __syncthreads();   // all QK reads of Kf done before P overlays it

    // P -> LDS in A-frag order: frag kv=mt>>1, lane''=((mt&1)*2+(quad>>1))*16+ln,
    // j=(quad&1)*4+r  (pairs r01 / r23 are u32-adjacent)
#pragma unroll
    for (int mt = 0; mt < 4; ++mt) {
      int base = (mt >> 1) * 512 + (((mt & 1) * 2 + (quad >> 1)) * 16 + ln) * 8 + (quad & 1) * 4;
      *(u32*)(Pw + base)     = packbf2(s[mt][0], s[mt][1]);
      *(u32*)(Pw + base + 2) = packbf2(s[mt][2], s[mt][3]);
    }

    // rescale O: alpha lives at lane ln (qrow); O rows are quad*4+r
    float ar[4];
#pragma unroll
    for (int r = 0; r < 4; ++r) ar[r] = __shfl(alpha, quad * 4 + r, 64);
#pragma unroll
    for (int n2 = 0; n2 < 8; ++n2)
#pragma unroll
      for (int r = 0; r < 4; ++r) o[n2][r] *= ar[r];

    // O += P·V
#pragma unroll
    for (int kv = 0; kv < 2; ++kv) {
      s8v ap = *(const s8v*)(Pl0 + kv * 512);
#pragma unroll
      for (int n2 = 0; n2 < 8; ++n2) {
        s8v bv = *(const s8v*)(Vl0 + (kv * 8 + n2) * 512);
        o[n2] = __builtin_amdgcn_mfma_f32_16x16x32_bf16(ap, bv, o[n2], 0, 0, 0);
      }
    }
    __syncthreads();   // PV reads done before restage overwrites Kf/Vf
  }

  // partials: unnormalized O (C-layout rows quad*4+r), per-qrow (m,l)
#pragma unroll
  for (int n2 = 0; n2 < 8; ++n2)
#pragma unroll
    for (int r = 0; r < 4; ++r) {
      size_t q = (size_t)b * L_Q + qb * 64 + w * 16 + quad * 4 + r;
      po[(q * KSPLIT + p) * DIM + n2 * 16 + ln] = o[n2][r];
    }
  if (quad == 0) {
    size_t q = (size_t)b * L_Q + qb * 64 + w * 16 + ln;
    *(float2*)&ml[(q * KSPLIT + p) * 2] = make_float2(mrow, lrow);
  }
}

// ---------------------------------------------------------------------------
// Combine splits: out[q] = sum_p 2^(m_p-M) O_p / sum_p l_p 2^(m_p-M)
// ---------------------------------------------------------------------------
__global__ __launch_bounds__(256) void combine(
    const float* __restrict__ po, const float* __restrict__ ml,
    float* __restrict__ out) {
  const int t = threadIdx.x;
  const int lr = t >> 5, l32 = t & 31;
  const size_t q = (size_t)blockIdx.x * 8 + lr;

  float m[KSPLIT], l[KSPLIT];
#pragma unroll
  for (int p = 0; p < KSPLIT; ++p) {
    m[p] = ml[(q * KSPLIT + p) * 2 + 0];
    l[p] = ml[(q * KSPLIT + p) * 2 + 1];
  }
  float M = m[0];
#pragma unroll
  for (int p = 1; p < KSPLIT; ++p) M = fmaxf(M, m[p]);
  float wp[KSPLIT], L = 0.f;
#pragma unroll
  for (int p = 0; p < KSPLIT; ++p) {
    wp[p] = __builtin_amdgcn_exp2f(fminf(m[p] - M, 0.f));
    L += l[p] * wp[p];
  }
  float invL = 1.0f / L;

  float4 acc = make_float4(0.f, 0.f, 0.f, 0.f);
#pragma unroll
  for (int p = 0; p < KSPLIT; ++p) {
    float4 v = *(const float4*)(po + (q * KSPLIT + p) * DIM + l32 * 4);
    acc.x += wp[p] * v.x; acc.y += wp[p] * v.y;
    acc.z += wp[p] * v.z; acc.w += wp[p] * v.w;
  }
  acc.x *= invL; acc.y *= invL; acc.z *= invL; acc.w *= invL;
  *(float4*)(out + q * DIM + l32 * 4) = acc;
}

extern "C" void kernel_launch(void* const* d_in, const int* in_sizes, int n_in,
                              void* d_out, int out_size, void* d_ws, size_t ws_size,
                              hipStream_t stream) {
  const float* query = (const float*)d_in[0];
  const float* key   = (const float*)d_in[1];
  const float* value = (const float*)d_in[2];
  const float* Wq    = (const float*)d_in[3];
  const float* Wk    = (const float*)d_in[4];
  const float* Wv    = (const float*)d_in[5];
  const int*   mask  = (const int*)d_in[6];
  float* out = (float*)d_out;

  u16* qp = (u16*)d_ws;
  u16* kp = qp + (size_t)B_N * L_Q * DIM;
  u16* vp = kp + (size_t)B_N * L_K * DIM;
  float* po = (float*)(vp + (size_t)B_N * DIM * L_K);   // 33.5 MB
  float* ml = po + (size_t)B_N * L_Q * KSPLIT * DIM;    // 0.5 MB

  hipLaunchKernelGGL(proj_mfma, dim3(768), dim3(256), 0, stream,
                     query, key, value, Wq, Wk, Wv, qp, kp, vp);
  hipLaunchKernelGGL(flash_split, dim3(1024), dim3(256), 0, stream,
                     qp, kp, vp, mask, po, ml);
  hipLaunchKernelGGL(combine, dim3((B_N * L_Q) / 8), dim3(256), 0, stream,
                     po, ml, out);
}